// Round 6
// baseline (371.757 us; speedup 1.0000x reference)
//
#include <hip/hip_runtime.h>
#include <hip/hip_bf16.h>

#define B_GR   16
#define N_PER  1024
#define M_PER  4096
#define NVEC   64
#define FDIM   192      // 3*NVEC
#define FSKIP  64
#define HID    256
#define ODIM   128
#define N_TOT  (B_GR * N_PER)   // 16384
#define M_TOT  (B_GR * M_PER)   // 65536

typedef __attribute__((ext_vector_type(8))) short short8v;   // 8 bf16 = 4 VGPR
typedef __attribute__((ext_vector_type(4))) float f32x4;     // MFMA acc

__device__ __forceinline__ unsigned short f2bf(float f) {
    __hip_bfloat16 h = __float2bfloat16(f);   // RNE
    return *reinterpret_cast<unsigned short*>(&h);
}

// swizzled element index into a [64][256] bf16 row-major LDS tile.
__device__ __forceinline__ int hsw(int r, int e) {
    return r * 256 + (e ^ ((r & 7) << 3));
}

// ---------------------------------------------------------------------------
// Kernel 0: weight prep — W1 [256,256] f32 -> bf16 [c][k], W2 likewise.
// ---------------------------------------------------------------------------
__global__ __launch_bounds__(256) void wprep_kernel(
    const float* __restrict__ W1, const float* __restrict__ W2,
    unsigned short* __restrict__ wt1, unsigned short* __restrict__ wt2)
{
    const int i = blockIdx.x * 256 + threadIdx.x;
    if (i < 256 * 256) {
        const int k = i >> 8, c = i & 255;
        wt1[c * 256 + k] = f2bf(W1[i]);
    } else {
        const int j = i - 256 * 256;
        const int k = j >> 7, c = j & 127;
        wt2[c * 256 + k] = f2bf(W2[j]);
    }
}

// ---------------------------------------------------------------------------
// Kernel 1: fully fused KNN + edge-transform + MFMA MLP.
// 512 threads (8 waves), 64 rows per block; 64 blocks per batch.
// Phase K: 32 lanes per QUERY-QUAD — each lane reads a candidate float4 once
//          and evaluates 4 queries (LDS traffic /4), branchless top-3 x4,
//          then 5-level shfl_xor lexicographic merge (lax.top_k tie-break).
// Phase U: one thread per (row,neighbor): U = Ry Rx^T pre-scaled by w/sum(w);
//          weights recomputed from the still-live pc cache (wL eliminated).
// Phase A: 27 FMA/row/lane via broadcast float4 reads of Usc.
// GEMM1/2: 16x16x32 bf16 MFMA, 2x4 wave grid (rows x cols) — halves
//          A-fragment LDS re-reads vs 1x8.
// LDS = 32768 (pc ∪ hb) + 7168 (Usc) + 768 (idxL) = 40704 B -> 4 blocks/CU.
// ---------------------------------------------------------------------------
__global__ __launch_bounds__(512, 8) void fused_kernel(
    const float* __restrict__ x,             // [N_TOT,192]
    const float* __restrict__ pos,           // [N_TOT,3]
    const float* __restrict__ pos_skip,      // [M_TOT,3]
    const float* __restrict__ x_skip,        // [M_TOT,64]
    const float* __restrict__ lframes,       // [N_TOT,3,3]
    const float* __restrict__ lframes_skip,  // [M_TOT,3,3]
    const unsigned short* __restrict__ wt1,  // [256][256] bf16 (c-major)
    const float* __restrict__ b1,            // [256]
    const unsigned short* __restrict__ wt2,  // [128][256] bf16 (c-major)
    const float* __restrict__ b2,            // [128]
    float* __restrict__ out)                 // [M_TOT,128]
{
    __shared__ __align__(16) char smraw[64 * 256 * 2];   // 32 KB: pc ∪ hb
    __shared__ __align__(16) float Usc[64 * 28];         // 7 KB scaled-U
    __shared__ int idxL[64 * 3];                         // LOCAL nbr indices

    float4*         pc = reinterpret_cast<float4*>(smraw);          // [1024]
    unsigned short* hb = reinterpret_cast<unsigned short*>(smraw);  // [64*256]

    const int tid  = threadIdx.x;
    const int lane = tid & 63;
    const int wv   = tid >> 6;               // 0..7
    const int blk  = blockIdx.x;
    const int lo   = lane & 15;
    const int hi   = lane >> 4;
    const int b    = blk >> 6;               // 64 blocks per batch

    // ---------------- Phase K: candidate cache + 4-query top-3 scan --------
    #pragma unroll
    for (int k = 0; k < 2; ++k) {
        const int j = tid + k * 512;
        const float* p = pos + (size_t)(b * N_PER + j) * 3;
        float a0 = p[0], a1 = p[1], a2 = p[2];
        pc[j] = make_float4(a0, a1, a2, a0*a0 + a1*a1 + a2*a2);
    }
    __syncthreads();

    {
        const int qg  = tid >> 5;            // query quad 0..15
        const int sub = tid & 31;
        const int qb  = blk * 64 + qg * 4;
        float qx[4], qy[4], qz[4], qq[4];
        #pragma unroll
        for (int u = 0; u < 4; ++u) {
            const float* qp = pos_skip + (size_t)(qb + u) * 3;
            qx[u] = qp[0]; qy[u] = qp[1]; qz[u] = qp[2];
            qq[u] = qx[u]*qx[u] + qy[u]*qy[u] + qz[u]*qz[u];
        }
        float d0[4], d1[4], d2[4];
        int   i0[4], i1[4], i2[4];
        #pragma unroll
        for (int u = 0; u < 4; ++u) {
            d0[u] = d1[u] = d2[u] = 1e30f;
            i0[u] = i1[u] = i2[u] = 0;
        }
        #pragma unroll 4
        for (int t = 0; t < 32; ++t) {
            const int j = t*32 + sub;        // 32 consecutive float4 / half-wave
            float4 c = pc[j];
            #pragma unroll
            for (int u = 0; u < 4; ++u) {
                float r = (qq[u] + c.w)
                        - 2.0f*(qx[u]*c.x + qy[u]*c.y + qz[u]*c.z);
                bool c0 = r < d0[u], c1 = r < d1[u], c2 = r < d2[u];
                i2[u] = c2 ? (c1 ? i1[u] : j) : i2[u];
                i1[u] = c1 ? (c0 ? i0[u] : j) : i1[u];
                i0[u] = c0 ? j : i0[u];
                d2[u] = c2 ? (c1 ? d1[u] : r) : d2[u];
                d1[u] = c1 ? (c0 ? d0[u] : r) : d1[u];
                d0[u] = c0 ? r : d0[u];
            }
        }
        // 5-level butterfly merge across 32 sublanes, lexicographic (d, j)
        #pragma unroll
        for (int mask = 1; mask <= 16; mask <<= 1) {
            #pragma unroll
            for (int u = 0; u < 4; ++u) {
                float e0 = __shfl_xor(d0[u], mask), e1 = __shfl_xor(d1[u], mask),
                      e2 = __shfl_xor(d2[u], mask);
                int   j0 = __shfl_xor(i0[u], mask), j1 = __shfl_xor(i1[u], mask),
                      j2 = __shfl_xor(i2[u], mask);
                const float ee[3] = {e0, e1, e2};
                const int   jj[3] = {j0, j1, j2};
                #pragma unroll
                for (int s = 0; s < 3; ++s) {
                    const float e = ee[s]; const int j = jj[s];
                    bool c0 = (e < d0[u]) || (e == d0[u] && j < i0[u]);
                    bool c1 = (e < d1[u]) || (e == d1[u] && j < i1[u]);
                    bool c2 = (e < d2[u]) || (e == d2[u] && j < i2[u]);
                    i2[u] = c2 ? (c1 ? i1[u] : j) : i2[u];
                    i1[u] = c1 ? (c0 ? i0[u] : j) : i1[u];
                    i0[u] = c0 ? j : i0[u];
                    d2[u] = c2 ? (c1 ? d1[u] : e) : d2[u];
                    d1[u] = c1 ? (c0 ? d0[u] : e) : d1[u];
                    d0[u] = c0 ? e : d0[u];
                }
            }
        }
        if (sub < 3) {
            #pragma unroll
            for (int u = 0; u < 4; ++u) {
                int v = (sub == 0) ? i0[u] : (sub == 1) ? i1[u] : i2[u];
                idxL[(qg*4 + u)*3 + sub] = v;          // local index
            }
        }
    }
    __syncthreads();   // idxL visible; pc still live (read by phase U)

    // ---------------- Phase U: scaled frame-change matrices (once) ----------
    {
        const int q = tid >> 3, sub = tid & 7;
        if (sub < 3) {
            const int m  = blk * 64 + q;
            const int j0 = idxL[q*3+0], j1 = idxL[q*3+1], j2 = idxL[q*3+2];
            const float qx = pos_skip[m*3+0], qy = pos_skip[m*3+1],
                        qz = pos_skip[m*3+2];
            float w[3];
            const int jls[3] = {j0, j1, j2};
            #pragma unroll
            for (int s = 0; s < 3; ++s) {
                float4 c = pc[jls[s]];
                float dx = c.x - qx, dy = c.y - qy, dz = c.z - qz;
                w[s] = 1.0f / fmaxf(dx*dx + dy*dy + dz*dz, 1e-16f);
            }
            const float wsub = (sub == 0) ? w[0] : (sub == 1) ? w[1] : w[2];
            const float sS   = wsub / (w[0] + w[1] + w[2]);
            const int   jl   = (sub == 0) ? j0 : (sub == 1) ? j1 : j2;
            const int   nb   = b * N_PER + jl;

            float RyS[9], Rx[9];
            #pragma unroll
            for (int t = 0; t < 9; ++t) RyS[t] = sS * lframes_skip[(size_t)m*9 + t];
            #pragma unroll
            for (int t = 0; t < 9; ++t) Rx[t] = lframes[(size_t)nb*9 + t];

            float* dst = &Usc[q*28 + sub*9];
            #pragma unroll
            for (int a = 0; a < 3; ++a)
                #pragma unroll
                for (int c = 0; c < 3; ++c)
                    dst[a*3+c] = RyS[a*3+0]*Rx[c*3+0]
                               + RyS[a*3+1]*Rx[c*3+1]
                               + RyS[a*3+2]*Rx[c*3+2];
        }
    }
    __syncthreads();

    // ---------------- Phase A: build h = [y | x_skip] (bf16) ----------------
    for (int rr = 0; rr < 8; ++rr) {
        const int r = wv * 8 + rr;
        const int m = blk * 64 + r;
        const int nbs[3] = {b*N_PER + idxL[r*3+0],
                            b*N_PER + idxL[r*3+1],
                            b*N_PER + idxL[r*3+2]};

        float Ub[28];
        float4* Ub4 = reinterpret_cast<float4*>(Ub);
        #pragma unroll
        for (int t = 0; t < 7; ++t)
            Ub4[t] = *reinterpret_cast<const float4*>(&Usc[r*28 + t*4]);  // bcast

        float n0 = 0.f, n1 = 0.f, n2 = 0.f;
        #pragma unroll
        for (int k = 0; k < 3; ++k) {
            const float* xp = x + (size_t)nbs[k]*FDIM + lane*3;
            const float v0 = xp[0], v1 = xp[1], v2 = xp[2];
            const int o = k*9;
            n0 += Ub[o+0]*v0 + Ub[o+1]*v1 + Ub[o+2]*v2;
            n1 += Ub[o+3]*v0 + Ub[o+4]*v1 + Ub[o+5]*v2;
            n2 += Ub[o+6]*v0 + Ub[o+7]*v1 + Ub[o+8]*v2;
        }
        hb[hsw(r, lane*3+0)] = f2bf(n0);
        hb[hsw(r, lane*3+1)] = f2bf(n1);
        hb[hsw(r, lane*3+2)] = f2bf(n2);
        hb[hsw(r, 192+lane)] = f2bf(x_skip[(size_t)m*FSKIP + lane]);
    }
    __syncthreads();

    // ---------------- GEMM1: hidden = relu(h @ W1 + b1), 2x4 wave grid ------
    const int wr = wv >> 2;   // row half  (0..1)  -> rows [wr*32, wr*32+32)
    const int wc = wv & 3;    // col quad  (0..3)  -> cols [wc*64, wc*64+64)

    f32x4 acc[2][4];
    #pragma unroll
    for (int fi = 0; fi < 2; ++fi)
        #pragma unroll
        for (int ci = 0; ci < 4; ++ci) acc[fi][ci] = (f32x4)0.f;

    for (int ks = 0; ks < 8; ++ks) {
        const int kk = ks*32 + hi*8;
        short8v a[2], bf[4];
        #pragma unroll
        for (int fi = 0; fi < 2; ++fi) {
            const int r = wr*32 + fi*16 + lo;
            a[fi] = *reinterpret_cast<const short8v*>(
                &hb[r*256 + (kk ^ ((lo & 7) << 3))]);
        }
        #pragma unroll
        for (int ci = 0; ci < 4; ++ci) {
            const int cb = wc*64 + ci*16 + lo;
            bf[ci] = *reinterpret_cast<const short8v*>(&wt1[cb*256 + kk]);
        }
        #pragma unroll
        for (int fi = 0; fi < 2; ++fi)
            #pragma unroll
            for (int ci = 0; ci < 4; ++ci)
                acc[fi][ci] = __builtin_amdgcn_mfma_f32_16x16x32_bf16(
                    a[fi], bf[ci], acc[fi][ci], 0, 0, 0);
    }
    __syncthreads();   // all GEMM1 reads of h complete

    {
        float b1v[4];
        #pragma unroll
        for (int ci = 0; ci < 4; ++ci) b1v[ci] = b1[wc*64 + ci*16 + lo];
        #pragma unroll
        for (int fi = 0; fi < 2; ++fi)
            #pragma unroll
            for (int ci = 0; ci < 4; ++ci)
                #pragma unroll
                for (int q = 0; q < 4; ++q) {
                    const int r = wr*32 + fi*16 + hi*4 + q;
                    const int c = wc*64 + ci*16 + lo;
                    hb[hsw(r, c)] = f2bf(fmaxf(acc[fi][ci][q] + b1v[ci], 0.f));
                }
    }
    __syncthreads();

    // ---------------- GEMM2: out = hidden @ W2 + b2, 2x4 wave grid ----------
    f32x4 acc2[2][2];
    #pragma unroll
    for (int fi = 0; fi < 2; ++fi)
        #pragma unroll
        for (int ci = 0; ci < 2; ++ci) acc2[fi][ci] = (f32x4)0.f;

    for (int ks = 0; ks < 8; ++ks) {
        const int kk = ks*32 + hi*8;
        short8v a[2], bf[2];
        #pragma unroll
        for (int fi = 0; fi < 2; ++fi) {
            const int r = wr*32 + fi*16 + lo;
            a[fi] = *reinterpret_cast<const short8v*>(
                &hb[r*256 + (kk ^ ((lo & 7) << 3))]);
        }
        #pragma unroll
        for (int ci = 0; ci < 2; ++ci) {
            const int cb = wc*32 + ci*16 + lo;
            bf[ci] = *reinterpret_cast<const short8v*>(&wt2[cb*256 + kk]);
        }
        #pragma unroll
        for (int fi = 0; fi < 2; ++fi)
            #pragma unroll
            for (int ci = 0; ci < 2; ++ci)
                acc2[fi][ci] = __builtin_amdgcn_mfma_f32_16x16x32_bf16(
                    a[fi], bf[ci], acc2[fi][ci], 0, 0, 0);
    }

    {
        float b2v[2];
        #pragma unroll
        for (int ci = 0; ci < 2; ++ci) b2v[ci] = b2[wc*32 + ci*16 + lo];
        #pragma unroll
        for (int fi = 0; fi < 2; ++fi)
            #pragma unroll
            for (int ci = 0; ci < 2; ++ci)
                #pragma unroll
                for (int q = 0; q < 4; ++q) {
                    const int r = wr*32 + fi*16 + hi*4 + q;
                    const int c = wc*32 + ci*16 + lo;
                    out[(size_t)(blk*64 + r)*ODIM + c] = acc2[fi][ci][q] + b2v[ci];
                }
    }
}

// ---------------------------------------------------------------------------
// Kernel 2: pass-through tail: pos_skip, batch_skip (int32), lframes_skip
// ---------------------------------------------------------------------------
__global__ __launch_bounds__(256) void tail_kernel(
    const float* __restrict__ pos_skip,
    const int*   __restrict__ batch_skip,
    const float* __restrict__ lframes_skip,
    float* __restrict__ dst)
{
    const int i = blockIdx.x * 256 + threadIdx.x;
    const int P = M_TOT * 3;
    const int Q = P + M_TOT;
    const int R = Q + M_TOT * 9;
    if (i < P)      dst[i] = pos_skip[i];
    else if (i < Q) dst[i] = (float)batch_skip[i - P];
    else if (i < R) dst[i] = lframes_skip[i - Q];
}

extern "C" void kernel_launch(void* const* d_in, const int* in_sizes, int n_in,
                              void* d_out, int out_size, void* d_ws, size_t ws_size,
                              hipStream_t stream) {
    const float* x            = (const float*)d_in[0];
    const float* pos          = (const float*)d_in[1];
    const float* pos_skip     = (const float*)d_in[2];
    const float* x_skip       = (const float*)d_in[3];
    const float* lframes      = (const float*)d_in[4];
    const float* lframes_skip = (const float*)d_in[5];
    const float* W1           = (const float*)d_in[6];
    const float* b1           = (const float*)d_in[7];
    const float* W2           = (const float*)d_in[8];
    const float* b2           = (const float*)d_in[9];
    const int*   batch_skip   = (const int*)d_in[11];

    char* ws = (char*)d_ws;
    unsigned short* wt1 = (unsigned short*)ws;                 // 131072 B
    unsigned short* wt2 = (unsigned short*)(ws + 131072);      // 65536 B
    float* out = (float*)d_out;

    wprep_kernel<<<(256*256 + 256*128) / 256, 256, 0, stream>>>(W1, W2, wt1, wt2);

    fused_kernel<<<M_TOT/64, 512, 0, stream>>>(x, pos, pos_skip, x_skip,
                                               lframes, lframes_skip,
                                               wt1, b1, wt2, b2, out);

    float* tail = out + (size_t)M_TOT * ODIM;
    const int tail_elems = M_TOT * (3 + 1 + 9);
    tail_kernel<<<(tail_elems + 255)/256, 256, 0, stream>>>(
        pos_skip, batch_skip, lframes_skip, tail);
}

// Round 7
// 186.182 us; speedup vs baseline: 1.9967x; 1.9967x over previous
//
#include <hip/hip_runtime.h>
#include <hip/hip_bf16.h>

#define B_GR   16
#define N_PER  1024
#define M_PER  4096
#define NVEC   64
#define FDIM   192      // 3*NVEC
#define FSKIP  64
#define HID    256
#define ODIM   128
#define N_TOT  (B_GR * N_PER)   // 16384
#define M_TOT  (B_GR * M_PER)   // 65536

typedef __attribute__((ext_vector_type(8))) short short8v;   // 8 bf16 = 4 VGPR
typedef __attribute__((ext_vector_type(4))) float f32x4;     // MFMA acc

__device__ __forceinline__ unsigned short f2bf(float f) {
    __hip_bfloat16 h = __float2bfloat16(f);   // RNE
    return *reinterpret_cast<unsigned short*>(&h);
}

// swizzled element index into a [64][256] bf16 row-major LDS tile.
__device__ __forceinline__ int hsw(int r, int e) {
    return r * 256 + (e ^ ((r & 7) << 3));
}

// ---------------------------------------------------------------------------
// Kernel 0: weight prep — W1 [256,256] f32 -> bf16 [c][k], W2 likewise.
// ---------------------------------------------------------------------------
__global__ __launch_bounds__(256) void wprep_kernel(
    const float* __restrict__ W1, const float* __restrict__ W2,
    unsigned short* __restrict__ wt1, unsigned short* __restrict__ wt2)
{
    const int i = blockIdx.x * 256 + threadIdx.x;
    if (i < 256 * 256) {
        const int k = i >> 8, c = i & 255;
        wt1[c * 256 + k] = f2bf(W1[i]);
    } else {
        const int j = i - 256 * 256;
        const int k = j >> 7, c = j & 127;
        wt2[c * 256 + k] = f2bf(W2[j]);
    }
}

// ---------------------------------------------------------------------------
// Kernel 1: fully fused KNN + edge-transform + MFMA MLP.
// 512 threads (8 waves), 64 rows per block; 64 blocks per batch.
// Phase K: 32 lanes per QUERY-QUAD — each lane reads a candidate float4 once
//          and evaluates 4 queries (LDS traffic /4), branchless top-3 x4,
//          then 5-level shfl_xor lexicographic merge (lax.top_k tie-break).
// Phase U: one thread per (row,neighbor): U = Ry Rx^T pre-scaled by w/sum(w);
//          weights recomputed from the still-live pc cache.
// Phase A: 27 FMA/row/lane via broadcast float4 reads of Usc.
// GEMM1/2: 16x16x32 bf16 MFMA, 2x4 wave grid (rows x cols).
// LDS = 32768 (pc ∪ hb) + 7168 (Usc) + 768 (idxL) = 40704 B (4 blocks/CU).
// __launch_bounds__(512, 5): round-6's (512,8) forced VGPR<=64 -> allocator
// spilled to scratch (VGPR 32, 1 GB WRITE_SIZE, 5x slowdown). (512,5) is the
// round-5-proven setting; occupancy then follows actual VGPR, no cliff.
// ---------------------------------------------------------------------------
__global__ __launch_bounds__(512, 5) void fused_kernel(
    const float* __restrict__ x,             // [N_TOT,192]
    const float* __restrict__ pos,           // [N_TOT,3]
    const float* __restrict__ pos_skip,      // [M_TOT,3]
    const float* __restrict__ x_skip,        // [M_TOT,64]
    const float* __restrict__ lframes,       // [N_TOT,3,3]
    const float* __restrict__ lframes_skip,  // [M_TOT,3,3]
    const unsigned short* __restrict__ wt1,  // [256][256] bf16 (c-major)
    const float* __restrict__ b1,            // [256]
    const unsigned short* __restrict__ wt2,  // [128][256] bf16 (c-major)
    const float* __restrict__ b2,            // [128]
    float* __restrict__ out)                 // [M_TOT,128]
{
    __shared__ __align__(16) char smraw[64 * 256 * 2];   // 32 KB: pc ∪ hb
    __shared__ __align__(16) float Usc[64 * 28];         // 7 KB scaled-U
    __shared__ int idxL[64 * 3];                         // LOCAL nbr indices

    float4*         pc = reinterpret_cast<float4*>(smraw);          // [1024]
    unsigned short* hb = reinterpret_cast<unsigned short*>(smraw);  // [64*256]

    const int tid  = threadIdx.x;
    const int lane = tid & 63;
    const int wv   = tid >> 6;               // 0..7
    const int blk  = blockIdx.x;
    const int lo   = lane & 15;
    const int hi   = lane >> 4;
    const int b    = blk >> 6;               // 64 blocks per batch

    // ---------------- Phase K: candidate cache + 4-query top-3 scan --------
    #pragma unroll
    for (int k = 0; k < 2; ++k) {
        const int j = tid + k * 512;
        const float* p = pos + (size_t)(b * N_PER + j) * 3;
        float a0 = p[0], a1 = p[1], a2 = p[2];
        pc[j] = make_float4(a0, a1, a2, a0*a0 + a1*a1 + a2*a2);
    }
    __syncthreads();

    {
        const int qg  = tid >> 5;            // query quad 0..15
        const int sub = tid & 31;
        const int qb  = blk * 64 + qg * 4;
        float qx[4], qy[4], qz[4], qq[4];
        #pragma unroll
        for (int u = 0; u < 4; ++u) {
            const float* qp = pos_skip + (size_t)(qb + u) * 3;
            qx[u] = qp[0]; qy[u] = qp[1]; qz[u] = qp[2];
            qq[u] = qx[u]*qx[u] + qy[u]*qy[u] + qz[u]*qz[u];
        }
        float d0[4], d1[4], d2[4];
        int   i0[4], i1[4], i2[4];
        #pragma unroll
        for (int u = 0; u < 4; ++u) {
            d0[u] = d1[u] = d2[u] = 1e30f;
            i0[u] = i1[u] = i2[u] = 0;
        }
        #pragma unroll 4
        for (int t = 0; t < 32; ++t) {
            const int j = t*32 + sub;        // 32 consecutive float4 / half-wave
            float4 c = pc[j];
            #pragma unroll
            for (int u = 0; u < 4; ++u) {
                float r = (qq[u] + c.w)
                        - 2.0f*(qx[u]*c.x + qy[u]*c.y + qz[u]*c.z);
                bool c0 = r < d0[u], c1 = r < d1[u], c2 = r < d2[u];
                i2[u] = c2 ? (c1 ? i1[u] : j) : i2[u];
                i1[u] = c1 ? (c0 ? i0[u] : j) : i1[u];
                i0[u] = c0 ? j : i0[u];
                d2[u] = c2 ? (c1 ? d1[u] : r) : d2[u];
                d1[u] = c1 ? (c0 ? d0[u] : r) : d1[u];
                d0[u] = c0 ? r : d0[u];
            }
        }
        // 5-level butterfly merge across 32 sublanes, lexicographic (d, j)
        #pragma unroll
        for (int mask = 1; mask <= 16; mask <<= 1) {
            #pragma unroll
            for (int u = 0; u < 4; ++u) {
                float e0 = __shfl_xor(d0[u], mask), e1 = __shfl_xor(d1[u], mask),
                      e2 = __shfl_xor(d2[u], mask);
                int   j0 = __shfl_xor(i0[u], mask), j1 = __shfl_xor(i1[u], mask),
                      j2 = __shfl_xor(i2[u], mask);
                const float ee[3] = {e0, e1, e2};
                const int   jj[3] = {j0, j1, j2};
                #pragma unroll
                for (int s = 0; s < 3; ++s) {
                    const float e = ee[s]; const int j = jj[s];
                    bool c0 = (e < d0[u]) || (e == d0[u] && j < i0[u]);
                    bool c1 = (e < d1[u]) || (e == d1[u] && j < i1[u]);
                    bool c2 = (e < d2[u]) || (e == d2[u] && j < i2[u]);
                    i2[u] = c2 ? (c1 ? i1[u] : j) : i2[u];
                    i1[u] = c1 ? (c0 ? i0[u] : j) : i1[u];
                    i0[u] = c0 ? j : i0[u];
                    d2[u] = c2 ? (c1 ? d1[u] : e) : d2[u];
                    d1[u] = c1 ? (c0 ? d0[u] : e) : d1[u];
                    d0[u] = c0 ? e : d0[u];
                }
            }
        }
        if (sub < 3) {
            #pragma unroll
            for (int u = 0; u < 4; ++u) {
                int v = (sub == 0) ? i0[u] : (sub == 1) ? i1[u] : i2[u];
                idxL[(qg*4 + u)*3 + sub] = v;          // local index
            }
        }
    }
    __syncthreads();   // idxL visible; pc still live (read by phase U)

    // ---------------- Phase U: scaled frame-change matrices (once) ----------
    {
        const int q = tid >> 3, sub = tid & 7;
        if (sub < 3) {
            const int m  = blk * 64 + q;
            const int j0 = idxL[q*3+0], j1 = idxL[q*3+1], j2 = idxL[q*3+2];
            const float qx = pos_skip[m*3+0], qy = pos_skip[m*3+1],
                        qz = pos_skip[m*3+2];
            float w[3];
            const int jls[3] = {j0, j1, j2};
            #pragma unroll
            for (int s = 0; s < 3; ++s) {
                float4 c = pc[jls[s]];
                float dx = c.x - qx, dy = c.y - qy, dz = c.z - qz;
                w[s] = 1.0f / fmaxf(dx*dx + dy*dy + dz*dz, 1e-16f);
            }
            const float wsub = (sub == 0) ? w[0] : (sub == 1) ? w[1] : w[2];
            const float sS   = wsub / (w[0] + w[1] + w[2]);
            const int   jl   = (sub == 0) ? j0 : (sub == 1) ? j1 : j2;
            const int   nb   = b * N_PER + jl;

            float RyS[9], Rx[9];
            #pragma unroll
            for (int t = 0; t < 9; ++t) RyS[t] = sS * lframes_skip[(size_t)m*9 + t];
            #pragma unroll
            for (int t = 0; t < 9; ++t) Rx[t] = lframes[(size_t)nb*9 + t];

            float* dst = &Usc[q*28 + sub*9];
            #pragma unroll
            for (int a = 0; a < 3; ++a)
                #pragma unroll
                for (int c = 0; c < 3; ++c)
                    dst[a*3+c] = RyS[a*3+0]*Rx[c*3+0]
                               + RyS[a*3+1]*Rx[c*3+1]
                               + RyS[a*3+2]*Rx[c*3+2];
        }
    }
    __syncthreads();

    // ---------------- Phase A: build h = [y | x_skip] (bf16) ----------------
    for (int rr = 0; rr < 8; ++rr) {
        const int r = wv * 8 + rr;
        const int m = blk * 64 + r;
        const int nbs[3] = {b*N_PER + idxL[r*3+0],
                            b*N_PER + idxL[r*3+1],
                            b*N_PER + idxL[r*3+2]};

        float Ub[28];
        float4* Ub4 = reinterpret_cast<float4*>(Ub);
        #pragma unroll
        for (int t = 0; t < 7; ++t)
            Ub4[t] = *reinterpret_cast<const float4*>(&Usc[r*28 + t*4]);  // bcast

        float n0 = 0.f, n1 = 0.f, n2 = 0.f;
        #pragma unroll
        for (int k = 0; k < 3; ++k) {
            const float* xp = x + (size_t)nbs[k]*FDIM + lane*3;
            const float v0 = xp[0], v1 = xp[1], v2 = xp[2];
            const int o = k*9;
            n0 += Ub[o+0]*v0 + Ub[o+1]*v1 + Ub[o+2]*v2;
            n1 += Ub[o+3]*v0 + Ub[o+4]*v1 + Ub[o+5]*v2;
            n2 += Ub[o+6]*v0 + Ub[o+7]*v1 + Ub[o+8]*v2;
        }
        hb[hsw(r, lane*3+0)] = f2bf(n0);
        hb[hsw(r, lane*3+1)] = f2bf(n1);
        hb[hsw(r, lane*3+2)] = f2bf(n2);
        hb[hsw(r, 192+lane)] = f2bf(x_skip[(size_t)m*FSKIP + lane]);
    }
    __syncthreads();

    // ---------------- GEMM1: hidden = relu(h @ W1 + b1), 2x4 wave grid ------
    const int wr = wv >> 2;   // row half  (0..1)  -> rows [wr*32, wr*32+32)
    const int wc = wv & 3;    // col quad  (0..3)  -> cols [wc*64, wc*64+64)

    f32x4 acc[2][4];
    #pragma unroll
    for (int fi = 0; fi < 2; ++fi)
        #pragma unroll
        for (int ci = 0; ci < 4; ++ci) acc[fi][ci] = (f32x4)0.f;

    for (int ks = 0; ks < 8; ++ks) {
        const int kk = ks*32 + hi*8;
        short8v a[2], bf[4];
        #pragma unroll
        for (int fi = 0; fi < 2; ++fi) {
            const int r = wr*32 + fi*16 + lo;
            a[fi] = *reinterpret_cast<const short8v*>(
                &hb[r*256 + (kk ^ ((lo & 7) << 3))]);
        }
        #pragma unroll
        for (int ci = 0; ci < 4; ++ci) {
            const int cb = wc*64 + ci*16 + lo;
            bf[ci] = *reinterpret_cast<const short8v*>(&wt1[cb*256 + kk]);
        }
        #pragma unroll
        for (int fi = 0; fi < 2; ++fi)
            #pragma unroll
            for (int ci = 0; ci < 4; ++ci)
                acc[fi][ci] = __builtin_amdgcn_mfma_f32_16x16x32_bf16(
                    a[fi], bf[ci], acc[fi][ci], 0, 0, 0);
    }
    __syncthreads();   // all GEMM1 reads of h complete

    {
        float b1v[4];
        #pragma unroll
        for (int ci = 0; ci < 4; ++ci) b1v[ci] = b1[wc*64 + ci*16 + lo];
        #pragma unroll
        for (int fi = 0; fi < 2; ++fi)
            #pragma unroll
            for (int ci = 0; ci < 4; ++ci)
                #pragma unroll
                for (int q = 0; q < 4; ++q) {
                    const int r = wr*32 + fi*16 + hi*4 + q;
                    const int c = wc*64 + ci*16 + lo;
                    hb[hsw(r, c)] = f2bf(fmaxf(acc[fi][ci][q] + b1v[ci], 0.f));
                }
    }
    __syncthreads();

    // ---------------- GEMM2: out = hidden @ W2 + b2, 2x4 wave grid ----------
    f32x4 acc2[2][2];
    #pragma unroll
    for (int fi = 0; fi < 2; ++fi)
        #pragma unroll
        for (int ci = 0; ci < 2; ++ci) acc2[fi][ci] = (f32x4)0.f;

    for (int ks = 0; ks < 8; ++ks) {
        const int kk = ks*32 + hi*8;
        short8v a[2], bf[2];
        #pragma unroll
        for (int fi = 0; fi < 2; ++fi) {
            const int r = wr*32 + fi*16 + lo;
            a[fi] = *reinterpret_cast<const short8v*>(
                &hb[r*256 + (kk ^ ((lo & 7) << 3))]);
        }
        #pragma unroll
        for (int ci = 0; ci < 2; ++ci) {
            const int cb = wc*32 + ci*16 + lo;
            bf[ci] = *reinterpret_cast<const short8v*>(&wt2[cb*256 + kk]);
        }
        #pragma unroll
        for (int fi = 0; fi < 2; ++fi)
            #pragma unroll
            for (int ci = 0; ci < 2; ++ci)
                acc2[fi][ci] = __builtin_amdgcn_mfma_f32_16x16x32_bf16(
                    a[fi], bf[ci], acc2[fi][ci], 0, 0, 0);
    }

    {
        float b2v[2];
        #pragma unroll
        for (int ci = 0; ci < 2; ++ci) b2v[ci] = b2[wc*32 + ci*16 + lo];
        #pragma unroll
        for (int fi = 0; fi < 2; ++fi)
            #pragma unroll
            for (int ci = 0; ci < 2; ++ci)
                #pragma unroll
                for (int q = 0; q < 4; ++q) {
                    const int r = wr*32 + fi*16 + hi*4 + q;
                    const int c = wc*32 + ci*16 + lo;
                    out[(size_t)(blk*64 + r)*ODIM + c] = acc2[fi][ci][q] + b2v[ci];
                }
    }
}

// ---------------------------------------------------------------------------
// Kernel 2: pass-through tail: pos_skip, batch_skip (int32), lframes_skip
// ---------------------------------------------------------------------------
__global__ __launch_bounds__(256) void tail_kernel(
    const float* __restrict__ pos_skip,
    const int*   __restrict__ batch_skip,
    const float* __restrict__ lframes_skip,
    float* __restrict__ dst)
{
    const int i = blockIdx.x * 256 + threadIdx.x;
    const int P = M_TOT * 3;
    const int Q = P + M_TOT;
    const int R = Q + M_TOT * 9;
    if (i < P)      dst[i] = pos_skip[i];
    else if (i < Q) dst[i] = (float)batch_skip[i - P];
    else if (i < R) dst[i] = lframes_skip[i - Q];
}

extern "C" void kernel_launch(void* const* d_in, const int* in_sizes, int n_in,
                              void* d_out, int out_size, void* d_ws, size_t ws_size,
                              hipStream_t stream) {
    const float* x            = (const float*)d_in[0];
    const float* pos          = (const float*)d_in[1];
    const float* pos_skip     = (const float*)d_in[2];
    const float* x_skip       = (const float*)d_in[3];
    const float* lframes      = (const float*)d_in[4];
    const float* lframes_skip = (const float*)d_in[5];
    const float* W1           = (const float*)d_in[6];
    const float* b1           = (const float*)d_in[7];
    const float* W2           = (const float*)d_in[8];
    const float* b2           = (const float*)d_in[9];
    const int*   batch_skip   = (const int*)d_in[11];

    char* ws = (char*)d_ws;
    unsigned short* wt1 = (unsigned short*)ws;                 // 131072 B
    unsigned short* wt2 = (unsigned short*)(ws + 131072);      // 65536 B
    float* out = (float*)d_out;

    wprep_kernel<<<(256*256 + 256*128) / 256, 256, 0, stream>>>(W1, W2, wt1, wt2);

    fused_kernel<<<M_TOT/64, 512, 0, stream>>>(x, pos, pos_skip, x_skip,
                                               lframes, lframes_skip,
                                               wt1, b1, wt2, b2, out);

    float* tail = out + (size_t)M_TOT * ODIM;
    const int tail_elems = M_TOT * (3 + 1 + 9);
    tail_kernel<<<(tail_elems + 255)/256, 256, 0, stream>>>(
        pos_skip, batch_skip, lframes_skip, tail);
}

// Round 8
// 153.462 us; speedup vs baseline: 2.4225x; 1.2132x over previous
//
#include <hip/hip_runtime.h>
#include <hip/hip_bf16.h>

#define B_GR   16
#define N_PER  1024
#define M_PER  4096
#define NVEC   64
#define FDIM   192      // 3*NVEC
#define FSKIP  64
#define HID    256
#define ODIM   128
#define N_TOT  (B_GR * N_PER)   // 16384
#define M_TOT  (B_GR * M_PER)   // 65536

typedef __attribute__((ext_vector_type(8))) short short8v;   // 8 bf16 = 4 VGPR
typedef __attribute__((ext_vector_type(4))) float f32x4;     // MFMA acc

__device__ __forceinline__ unsigned short f2bf(float f) {
    __hip_bfloat16 h = __float2bfloat16(f);   // RNE
    return *reinterpret_cast<unsigned short*>(&h);
}

// swizzled element index into a [64][256] bf16 row-major LDS tile.
__device__ __forceinline__ int hsw(int r, int e) {
    return r * 256 + (e ^ ((r & 7) << 3));
}

// ---------------------------------------------------------------------------
// Kernel 0: weight prep — W1 [256,256] f32 -> bf16 [c][k], W2 likewise.
// ---------------------------------------------------------------------------
__global__ __launch_bounds__(256) void wprep_kernel(
    const float* __restrict__ W1, const float* __restrict__ W2,
    unsigned short* __restrict__ wt1, unsigned short* __restrict__ wt2)
{
    const int i = blockIdx.x * 256 + threadIdx.x;
    if (i < 256 * 256) {
        const int k = i >> 8, c = i & 255;
        wt1[c * 256 + k] = f2bf(W1[i]);
    } else {
        const int j = i - 256 * 256;
        const int k = j >> 7, c = j & 127;
        wt2[c * 256 + k] = f2bf(W2[j]);
    }
}

// ---------------------------------------------------------------------------
// Kernel 1: fully fused KNN + edge-transform + MFMA MLP.
// 512 threads (8 waves), 64 rows per block; 64 blocks per batch.
// LAUNCH BOUNDS LOG (empirical, this toolchain): 2nd arg = min BLOCKS/CU.
//   (512,8) -> VGPR cap 32: catastrophic spill (1 GB scratch, 394 us)
//   (512,5) -> VGPR cap 48: still spills ~300 MB (this code needs ~80), 194 us
//   (512,2) -> VGPR cap 128: natural footprint, no spill   <- this round
// Phase K: 32 lanes per QUERY-QUAD — each lane reads a candidate float4 once
//          and evaluates 4 queries (LDS traffic /4), branchless top-3 x4,
//          then 5-level shfl_xor lexicographic merge (lax.top_k tie-break).
// Phase U: one thread per (row,neighbor): U = Ry Rx^T pre-scaled by w/sum(w).
// Phase A: 27 FMA/row/lane via broadcast float4 reads of Usc.
// GEMM1/2: 16x16x32 bf16 MFMA, 2x4 wave grid (rows x cols).
// LDS = 32768 (pc ∪ hb) + 7168 (Usc) + 768 (idxL) = 40704 B.
// ---------------------------------------------------------------------------
__global__ __launch_bounds__(512, 2) void fused_kernel(
    const float* __restrict__ x,             // [N_TOT,192]
    const float* __restrict__ pos,           // [N_TOT,3]
    const float* __restrict__ pos_skip,      // [M_TOT,3]
    const float* __restrict__ x_skip,        // [M_TOT,64]
    const float* __restrict__ lframes,       // [N_TOT,3,3]
    const float* __restrict__ lframes_skip,  // [M_TOT,3,3]
    const unsigned short* __restrict__ wt1,  // [256][256] bf16 (c-major)
    const float* __restrict__ b1,            // [256]
    const unsigned short* __restrict__ wt2,  // [128][256] bf16 (c-major)
    const float* __restrict__ b2,            // [128]
    float* __restrict__ out)                 // [M_TOT,128]
{
    __shared__ __align__(16) char smraw[64 * 256 * 2];   // 32 KB: pc ∪ hb
    __shared__ __align__(16) float Usc[64 * 28];         // 7 KB scaled-U
    __shared__ int idxL[64 * 3];                         // LOCAL nbr indices

    float4*         pc = reinterpret_cast<float4*>(smraw);          // [1024]
    unsigned short* hb = reinterpret_cast<unsigned short*>(smraw);  // [64*256]

    const int tid  = threadIdx.x;
    const int lane = tid & 63;
    const int wv   = tid >> 6;               // 0..7
    const int blk  = blockIdx.x;
    const int lo   = lane & 15;
    const int hi   = lane >> 4;
    const int b    = blk >> 6;               // 64 blocks per batch

    // ---------------- Phase K: candidate cache + 4-query top-3 scan --------
    #pragma unroll
    for (int k = 0; k < 2; ++k) {
        const int j = tid + k * 512;
        const float* p = pos + (size_t)(b * N_PER + j) * 3;
        float a0 = p[0], a1 = p[1], a2 = p[2];
        pc[j] = make_float4(a0, a1, a2, a0*a0 + a1*a1 + a2*a2);
    }
    __syncthreads();

    {
        const int qg  = tid >> 5;            // query quad 0..15
        const int sub = tid & 31;
        const int qb  = blk * 64 + qg * 4;
        float qx[4], qy[4], qz[4], qq[4];
        #pragma unroll
        for (int u = 0; u < 4; ++u) {
            const float* qp = pos_skip + (size_t)(qb + u) * 3;
            qx[u] = qp[0]; qy[u] = qp[1]; qz[u] = qp[2];
            qq[u] = qx[u]*qx[u] + qy[u]*qy[u] + qz[u]*qz[u];
        }
        float d0[4], d1[4], d2[4];
        int   i0[4], i1[4], i2[4];
        #pragma unroll
        for (int u = 0; u < 4; ++u) {
            d0[u] = d1[u] = d2[u] = 1e30f;
            i0[u] = i1[u] = i2[u] = 0;
        }
        #pragma unroll 4
        for (int t = 0; t < 32; ++t) {
            const int j = t*32 + sub;        // 32 consecutive float4 / half-wave
            float4 c = pc[j];
            #pragma unroll
            for (int u = 0; u < 4; ++u) {
                float r = (qq[u] + c.w)
                        - 2.0f*(qx[u]*c.x + qy[u]*c.y + qz[u]*c.z);
                bool c0 = r < d0[u], c1 = r < d1[u], c2 = r < d2[u];
                i2[u] = c2 ? (c1 ? i1[u] : j) : i2[u];
                i1[u] = c1 ? (c0 ? i0[u] : j) : i1[u];
                i0[u] = c0 ? j : i0[u];
                d2[u] = c2 ? (c1 ? d1[u] : r) : d2[u];
                d1[u] = c1 ? (c0 ? d0[u] : r) : d1[u];
                d0[u] = c0 ? r : d0[u];
            }
        }
        // 5-level butterfly merge across 32 sublanes, lexicographic (d, j)
        #pragma unroll
        for (int mask = 1; mask <= 16; mask <<= 1) {
            #pragma unroll
            for (int u = 0; u < 4; ++u) {
                float e0 = __shfl_xor(d0[u], mask), e1 = __shfl_xor(d1[u], mask),
                      e2 = __shfl_xor(d2[u], mask);
                int   j0 = __shfl_xor(i0[u], mask), j1 = __shfl_xor(i1[u], mask),
                      j2 = __shfl_xor(i2[u], mask);
                const float ee[3] = {e0, e1, e2};
                const int   jj[3] = {j0, j1, j2};
                #pragma unroll
                for (int s = 0; s < 3; ++s) {
                    const float e = ee[s]; const int j = jj[s];
                    bool c0 = (e < d0[u]) || (e == d0[u] && j < i0[u]);
                    bool c1 = (e < d1[u]) || (e == d1[u] && j < i1[u]);
                    bool c2 = (e < d2[u]) || (e == d2[u] && j < i2[u]);
                    i2[u] = c2 ? (c1 ? i1[u] : j) : i2[u];
                    i1[u] = c1 ? (c0 ? i0[u] : j) : i1[u];
                    i0[u] = c0 ? j : i0[u];
                    d2[u] = c2 ? (c1 ? d1[u] : e) : d2[u];
                    d1[u] = c1 ? (c0 ? d0[u] : e) : d1[u];
                    d0[u] = c0 ? e : d0[u];
                }
            }
        }
        if (sub < 3) {
            #pragma unroll
            for (int u = 0; u < 4; ++u) {
                int v = (sub == 0) ? i0[u] : (sub == 1) ? i1[u] : i2[u];
                idxL[(qg*4 + u)*3 + sub] = v;          // local index
            }
        }
    }
    __syncthreads();   // idxL visible; pc still live (read by phase U)

    // ---------------- Phase U: scaled frame-change matrices (once) ----------
    {
        const int q = tid >> 3, sub = tid & 7;
        if (sub < 3) {
            const int m  = blk * 64 + q;
            const int j0 = idxL[q*3+0], j1 = idxL[q*3+1], j2 = idxL[q*3+2];
            const float qx = pos_skip[m*3+0], qy = pos_skip[m*3+1],
                        qz = pos_skip[m*3+2];
            float w[3];
            const int jls[3] = {j0, j1, j2};
            #pragma unroll
            for (int s = 0; s < 3; ++s) {
                float4 c = pc[jls[s]];
                float dx = c.x - qx, dy = c.y - qy, dz = c.z - qz;
                w[s] = 1.0f / fmaxf(dx*dx + dy*dy + dz*dz, 1e-16f);
            }
            const float wsub = (sub == 0) ? w[0] : (sub == 1) ? w[1] : w[2];
            const float sS   = wsub / (w[0] + w[1] + w[2]);
            const int   jl   = (sub == 0) ? j0 : (sub == 1) ? j1 : j2;
            const int   nb   = b * N_PER + jl;

            float RyS[9], Rx[9];
            #pragma unroll
            for (int t = 0; t < 9; ++t) RyS[t] = sS * lframes_skip[(size_t)m*9 + t];
            #pragma unroll
            for (int t = 0; t < 9; ++t) Rx[t] = lframes[(size_t)nb*9 + t];

            float* dst = &Usc[q*28 + sub*9];
            #pragma unroll
            for (int a = 0; a < 3; ++a)
                #pragma unroll
                for (int c = 0; c < 3; ++c)
                    dst[a*3+c] = RyS[a*3+0]*Rx[c*3+0]
                               + RyS[a*3+1]*Rx[c*3+1]
                               + RyS[a*3+2]*Rx[c*3+2];
        }
    }
    __syncthreads();

    // ---------------- Phase A: build h = [y | x_skip] (bf16) ----------------
    for (int rr = 0; rr < 8; ++rr) {
        const int r = wv * 8 + rr;
        const int m = blk * 64 + r;
        const int nbs[3] = {b*N_PER + idxL[r*3+0],
                            b*N_PER + idxL[r*3+1],
                            b*N_PER + idxL[r*3+2]};

        float Ub[28];
        float4* Ub4 = reinterpret_cast<float4*>(Ub);
        #pragma unroll
        for (int t = 0; t < 7; ++t)
            Ub4[t] = *reinterpret_cast<const float4*>(&Usc[r*28 + t*4]);  // bcast

        float n0 = 0.f, n1 = 0.f, n2 = 0.f;
        #pragma unroll
        for (int k = 0; k < 3; ++k) {
            const float* xp = x + (size_t)nbs[k]*FDIM + lane*3;
            const float v0 = xp[0], v1 = xp[1], v2 = xp[2];
            const int o = k*9;
            n0 += Ub[o+0]*v0 + Ub[o+1]*v1 + Ub[o+2]*v2;
            n1 += Ub[o+3]*v0 + Ub[o+4]*v1 + Ub[o+5]*v2;
            n2 += Ub[o+6]*v0 + Ub[o+7]*v1 + Ub[o+8]*v2;
        }
        hb[hsw(r, lane*3+0)] = f2bf(n0);
        hb[hsw(r, lane*3+1)] = f2bf(n1);
        hb[hsw(r, lane*3+2)] = f2bf(n2);
        hb[hsw(r, 192+lane)] = f2bf(x_skip[(size_t)m*FSKIP + lane]);
    }
    __syncthreads();

    // ---------------- GEMM1: hidden = relu(h @ W1 + b1), 2x4 wave grid ------
    const int wr = wv >> 2;   // row half  (0..1)  -> rows [wr*32, wr*32+32)
    const int wc = wv & 3;    // col quad  (0..3)  -> cols [wc*64, wc*64+64)

    f32x4 acc[2][4];
    #pragma unroll
    for (int fi = 0; fi < 2; ++fi)
        #pragma unroll
        for (int ci = 0; ci < 4; ++ci) acc[fi][ci] = (f32x4)0.f;

    for (int ks = 0; ks < 8; ++ks) {
        const int kk = ks*32 + hi*8;
        short8v a[2], bf[4];
        #pragma unroll
        for (int fi = 0; fi < 2; ++fi) {
            const int r = wr*32 + fi*16 + lo;
            a[fi] = *reinterpret_cast<const short8v*>(
                &hb[r*256 + (kk ^ ((lo & 7) << 3))]);
        }
        #pragma unroll
        for (int ci = 0; ci < 4; ++ci) {
            const int cb = wc*64 + ci*16 + lo;
            bf[ci] = *reinterpret_cast<const short8v*>(&wt1[cb*256 + kk]);
        }
        #pragma unroll
        for (int fi = 0; fi < 2; ++fi)
            #pragma unroll
            for (int ci = 0; ci < 4; ++ci)
                acc[fi][ci] = __builtin_amdgcn_mfma_f32_16x16x32_bf16(
                    a[fi], bf[ci], acc[fi][ci], 0, 0, 0);
    }
    __syncthreads();   // all GEMM1 reads of h complete

    {
        float b1v[4];
        #pragma unroll
        for (int ci = 0; ci < 4; ++ci) b1v[ci] = b1[wc*64 + ci*16 + lo];
        #pragma unroll
        for (int fi = 0; fi < 2; ++fi)
            #pragma unroll
            for (int ci = 0; ci < 4; ++ci)
                #pragma unroll
                for (int q = 0; q < 4; ++q) {
                    const int r = wr*32 + fi*16 + hi*4 + q;
                    const int c = wc*64 + ci*16 + lo;
                    hb[hsw(r, c)] = f2bf(fmaxf(acc[fi][ci][q] + b1v[ci], 0.f));
                }
    }
    __syncthreads();

    // ---------------- GEMM2: out = hidden @ W2 + b2, 2x4 wave grid ----------
    f32x4 acc2[2][2];
    #pragma unroll
    for (int fi = 0; fi < 2; ++fi)
        #pragma unroll
        for (int ci = 0; ci < 2; ++ci) acc2[fi][ci] = (f32x4)0.f;

    for (int ks = 0; ks < 8; ++ks) {
        const int kk = ks*32 + hi*8;
        short8v a[2], bf[2];
        #pragma unroll
        for (int fi = 0; fi < 2; ++fi) {
            const int r = wr*32 + fi*16 + lo;
            a[fi] = *reinterpret_cast<const short8v*>(
                &hb[r*256 + (kk ^ ((lo & 7) << 3))]);
        }
        #pragma unroll
        for (int ci = 0; ci < 2; ++ci) {
            const int cb = wc*32 + ci*16 + lo;
            bf[ci] = *reinterpret_cast<const short8v*>(&wt2[cb*256 + kk]);
        }
        #pragma unroll
        for (int fi = 0; fi < 2; ++fi)
            #pragma unroll
            for (int ci = 0; ci < 2; ++ci)
                acc2[fi][ci] = __builtin_amdgcn_mfma_f32_16x16x32_bf16(
                    a[fi], bf[ci], acc2[fi][ci], 0, 0, 0);
    }

    {
        float b2v[2];
        #pragma unroll
        for (int ci = 0; ci < 2; ++ci) b2v[ci] = b2[wc*32 + ci*16 + lo];
        #pragma unroll
        for (int fi = 0; fi < 2; ++fi)
            #pragma unroll
            for (int ci = 0; ci < 2; ++ci)
                #pragma unroll
                for (int q = 0; q < 4; ++q) {
                    const int r = wr*32 + fi*16 + hi*4 + q;
                    const int c = wc*32 + ci*16 + lo;
                    out[(size_t)(blk*64 + r)*ODIM + c] = acc2[fi][ci][q] + b2v[ci];
                }
    }
}

// ---------------------------------------------------------------------------
// Kernel 2: pass-through tail: pos_skip, batch_skip (int32), lframes_skip
// ---------------------------------------------------------------------------
__global__ __launch_bounds__(256) void tail_kernel(
    const float* __restrict__ pos_skip,
    const int*   __restrict__ batch_skip,
    const float* __restrict__ lframes_skip,
    float* __restrict__ dst)
{
    const int i = blockIdx.x * 256 + threadIdx.x;
    const int P = M_TOT * 3;
    const int Q = P + M_TOT;
    const int R = Q + M_TOT * 9;
    if (i < P)      dst[i] = pos_skip[i];
    else if (i < Q) dst[i] = (float)batch_skip[i - P];
    else if (i < R) dst[i] = lframes_skip[i - Q];
}

extern "C" void kernel_launch(void* const* d_in, const int* in_sizes, int n_in,
                              void* d_out, int out_size, void* d_ws, size_t ws_size,
                              hipStream_t stream) {
    const float* x            = (const float*)d_in[0];
    const float* pos          = (const float*)d_in[1];
    const float* pos_skip     = (const float*)d_in[2];
    const float* x_skip       = (const float*)d_in[3];
    const float* lframes      = (const float*)d_in[4];
    const float* lframes_skip = (const float*)d_in[5];
    const float* W1           = (const float*)d_in[6];
    const float* b1           = (const float*)d_in[7];
    const float* W2           = (const float*)d_in[8];
    const float* b2           = (const float*)d_in[9];
    const int*   batch_skip   = (const int*)d_in[11];

    char* ws = (char*)d_ws;
    unsigned short* wt1 = (unsigned short*)ws;                 // 131072 B
    unsigned short* wt2 = (unsigned short*)(ws + 131072);      // 65536 B
    float* out = (float*)d_out;

    wprep_kernel<<<(256*256 + 256*128) / 256, 256, 0, stream>>>(W1, W2, wt1, wt2);

    fused_kernel<<<M_TOT/64, 512, 0, stream>>>(x, pos, pos_skip, x_skip,
                                               lframes, lframes_skip,
                                               wt1, b1, wt2, b2, out);

    float* tail = out + (size_t)M_TOT * ODIM;
    const int tail_elems = M_TOT * (3 + 1 + 9);
    tail_kernel<<<(tail_elems + 255)/256, 256, 0, stream>>>(
        pos_skip, batch_skip, lframes_skip, tail);
}

// Round 9
// 74.168 us; speedup vs baseline: 5.0123x; 2.0691x over previous
//
#include <hip/hip_runtime.h>
#include <hip/hip_bf16.h>

#define B_GR   16
#define N_PER  1024
#define M_PER  4096
#define NVEC   64
#define FDIM   192      // 3*NVEC
#define FSKIP  64
#define HID    256
#define ODIM   128
#define N_TOT  (B_GR * N_PER)   // 16384
#define M_TOT  (B_GR * M_PER)   // 65536

typedef __attribute__((ext_vector_type(8))) short short8v;   // 8 bf16 = 4 VGPR
typedef __attribute__((ext_vector_type(4))) float f32x4;     // MFMA acc

__device__ __forceinline__ unsigned short f2bf(float f) {
    __hip_bfloat16 h = __float2bfloat16(f);   // RNE
    return *reinterpret_cast<unsigned short*>(&h);
}

// swizzled element index into a [64][256] bf16 row-major LDS tile.
__device__ __forceinline__ int hsw(int r, int e) {
    return r * 256 + (e ^ ((r & 7) << 3));
}

// ---------------------------------------------------------------------------
// Kernel 0: weight prep — W1 [256,256] f32 -> bf16 [c][k], W2 likewise.
// ---------------------------------------------------------------------------
__global__ __launch_bounds__(256) void wprep_kernel(
    const float* __restrict__ W1, const float* __restrict__ W2,
    unsigned short* __restrict__ wt1, unsigned short* __restrict__ wt2)
{
    const int i = blockIdx.x * 256 + threadIdx.x;
    if (i < 256 * 256) {
        const int k = i >> 8, c = i & 255;
        wt1[c * 256 + k] = f2bf(W1[i]);
    } else {
        const int j = i - 256 * 256;
        const int k = j >> 7, c = j & 127;
        wt2[c * 256 + k] = f2bf(W2[j]);
    }
}

// ---------------------------------------------------------------------------
// Kernel 1: fully fused KNN + edge-transform + MFMA MLP.
// ROUND-5 STRUCTURE RESTORED (proven 79.5 us); single change: wL LDS array
// removed (phase U recomputes weights from pc) -> LDS 41472 -> 40704 B =
// exactly 4 blocks/CU (was 3).
// HISTORY (do not regress):
//   r6: 4-query phase K + (512,8): VGPR cap 32, HBM spill, 394 us
//   r7: same + (512,5): cap 48, still spills, 194 us
//   r8: same + (512,2): VGPR 64, no HBM spill but structure itself slow
//       (2x VALU-busy time vs r5: fat live-set scan + 60-step merge), 157 us
// Phase K: 8 lanes per query, interleaved eighths, branchless top-3,
//          3-level shfl_xor lexicographic merge (lax.top_k tie-break).
// Phase U: one thread per (row,neighbor): U = Ry Rx^T pre-scaled by w/sum(w),
//          weights recomputed from the still-live pc cache.
// Phase A: 27 FMA/row/lane via broadcast float4 reads of Usc.
// GEMM1/2: 16x16x32 bf16 MFMA; wave wv covers 32 (GEMM1) / 16 (GEMM2) cols.
// ---------------------------------------------------------------------------
__global__ __launch_bounds__(512, 2) void fused_kernel(
    const float* __restrict__ x,             // [N_TOT,192]
    const float* __restrict__ pos,           // [N_TOT,3]
    const float* __restrict__ pos_skip,      // [M_TOT,3]
    const float* __restrict__ x_skip,        // [M_TOT,64]
    const float* __restrict__ lframes,       // [N_TOT,3,3]
    const float* __restrict__ lframes_skip,  // [M_TOT,3,3]
    const unsigned short* __restrict__ wt1,  // [256][256] bf16 (c-major)
    const float* __restrict__ b1,            // [256]
    const unsigned short* __restrict__ wt2,  // [128][256] bf16 (c-major)
    const float* __restrict__ b2,            // [128]
    float* __restrict__ out)                 // [M_TOT,128]
{
    __shared__ __align__(16) char smraw[64 * 256 * 2];   // 32 KB: pc ∪ hb
    __shared__ __align__(16) float Usc[64 * 28];         // 7 KB scaled-U
    __shared__ int idxL[64 * 3];                         // LOCAL nbr indices

    float4*         pc = reinterpret_cast<float4*>(smraw);          // [1024]
    unsigned short* hb = reinterpret_cast<unsigned short*>(smraw);  // [64*256]

    const int tid  = threadIdx.x;
    const int lane = tid & 63;
    const int wv   = tid >> 6;               // 0..7
    const int blk  = blockIdx.x;
    const int lo   = lane & 15;
    const int hi   = lane >> 4;
    const int b    = blk >> 6;               // 64 blocks per batch

    // ---------------- Phase K: candidate cache + top-3 scan ----------------
    #pragma unroll
    for (int k = 0; k < 2; ++k) {
        const int j = tid + k * 512;
        const float* p = pos + (size_t)(b * N_PER + j) * 3;
        float a0 = p[0], a1 = p[1], a2 = p[2];
        pc[j] = make_float4(a0, a1, a2, a0*a0 + a1*a1 + a2*a2);
    }
    __syncthreads();

    {
        const int q   = tid >> 3;            // query row 0..63
        const int sub = tid & 7;
        const int m   = blk * 64 + q;
        const float qx = pos_skip[m*3+0], qy = pos_skip[m*3+1], qz = pos_skip[m*3+2];
        const float qq = qx*qx + qy*qy + qz*qz;

        float d0 = 1e30f, d1 = 1e30f, d2 = 1e30f;
        int   i0 = 0,     i1 = 0,     i2 = 0;
        #pragma unroll 4
        for (int t = 0; t < 128; ++t) {
            const int j = t*8 + sub;         // wave reads 128B bcast x8
            float4 c = pc[j];
            float r = (qq + c.w) - 2.0f * (qx*c.x + qy*c.y + qz*c.z);
            bool c0 = r < d0, c1 = r < d1, c2 = r < d2;
            i2 = c2 ? (c1 ? i1 : j) : i2;
            i1 = c1 ? (c0 ? i0 : j) : i1;
            i0 = c0 ? j : i0;
            d2 = c2 ? (c1 ? d1 : r) : d2;
            d1 = c1 ? (c0 ? d0 : r) : d1;
            d0 = c0 ? r : d0;
        }
        // 3-level butterfly merge across the 8 sublanes, lexicographic (d, j)
        #pragma unroll
        for (int mask = 1; mask <= 4; mask <<= 1) {
            float e0 = __shfl_xor(d0, mask), e1 = __shfl_xor(d1, mask),
                  e2 = __shfl_xor(d2, mask);
            int   j0 = __shfl_xor(i0, mask), j1 = __shfl_xor(i1, mask),
                  j2 = __shfl_xor(i2, mask);
            const float ee[3] = {e0, e1, e2};
            const int   jj[3] = {j0, j1, j2};
            #pragma unroll
            for (int s = 0; s < 3; ++s) {
                const float e = ee[s]; const int j = jj[s];
                bool c0 = (e < d0) || (e == d0 && j < i0);
                bool c1 = (e < d1) || (e == d1 && j < i1);
                bool c2 = (e < d2) || (e == d2 && j < i2);
                i2 = c2 ? (c1 ? i1 : j) : i2;
                i1 = c1 ? (c0 ? i0 : j) : i1;
                i0 = c0 ? j : i0;
                d2 = c2 ? (c1 ? d1 : e) : d2;
                d1 = c1 ? (c0 ? d0 : e) : d1;
                d0 = c0 ? e : d0;
            }
        }
        if (sub < 3) {
            const int jl = (sub == 0) ? i0 : (sub == 1) ? i1 : i2;
            idxL[q*3 + sub] = jl;            // local index
        }
    }
    __syncthreads();   // idxL visible; pc still live (read by phase U)

    // ---------------- Phase U: scaled frame-change matrices (once) ----------
    {
        const int q = tid >> 3, sub = tid & 7;
        if (sub < 3) {
            const int m  = blk * 64 + q;
            const int j0 = idxL[q*3+0], j1 = idxL[q*3+1], j2 = idxL[q*3+2];
            const float qx = pos_skip[m*3+0], qy = pos_skip[m*3+1],
                        qz = pos_skip[m*3+2];
            float w[3];
            const int jls[3] = {j0, j1, j2};
            #pragma unroll
            for (int s = 0; s < 3; ++s) {
                float4 c = pc[jls[s]];
                float dx = c.x - qx, dy = c.y - qy, dz = c.z - qz;
                w[s] = 1.0f / fmaxf(dx*dx + dy*dy + dz*dz, 1e-16f);
            }
            const float wsub = (sub == 0) ? w[0] : (sub == 1) ? w[1] : w[2];
            const float sS   = wsub / (w[0] + w[1] + w[2]);
            const int   jl   = (sub == 0) ? j0 : (sub == 1) ? j1 : j2;
            const int   nb   = b * N_PER + jl;

            float RyS[9], Rx[9];
            #pragma unroll
            for (int t = 0; t < 9; ++t) RyS[t] = sS * lframes_skip[(size_t)m*9 + t];
            #pragma unroll
            for (int t = 0; t < 9; ++t) Rx[t] = lframes[(size_t)nb*9 + t];

            float* dst = &Usc[q*28 + sub*9];
            #pragma unroll
            for (int a = 0; a < 3; ++a)
                #pragma unroll
                for (int c = 0; c < 3; ++c)
                    dst[a*3+c] = RyS[a*3+0]*Rx[c*3+0]
                               + RyS[a*3+1]*Rx[c*3+1]
                               + RyS[a*3+2]*Rx[c*3+2];
        }
    }
    __syncthreads();

    // ---------------- Phase A: build h = [y | x_skip] (bf16) ----------------
    for (int rr = 0; rr < 8; ++rr) {
        const int r = wv * 8 + rr;
        const int m = blk * 64 + r;
        const int nbs[3] = {b*N_PER + idxL[r*3+0],
                            b*N_PER + idxL[r*3+1],
                            b*N_PER + idxL[r*3+2]};

        float Ub[28];
        float4* Ub4 = reinterpret_cast<float4*>(Ub);
        #pragma unroll
        for (int t = 0; t < 7; ++t)
            Ub4[t] = *reinterpret_cast<const float4*>(&Usc[r*28 + t*4]);  // bcast

        float n0 = 0.f, n1 = 0.f, n2 = 0.f;
        #pragma unroll
        for (int k = 0; k < 3; ++k) {
            const float* xp = x + (size_t)nbs[k]*FDIM + lane*3;
            const float v0 = xp[0], v1 = xp[1], v2 = xp[2];
            const int o = k*9;
            n0 += Ub[o+0]*v0 + Ub[o+1]*v1 + Ub[o+2]*v2;
            n1 += Ub[o+3]*v0 + Ub[o+4]*v1 + Ub[o+5]*v2;
            n2 += Ub[o+6]*v0 + Ub[o+7]*v1 + Ub[o+8]*v2;
        }
        hb[hsw(r, lane*3+0)] = f2bf(n0);
        hb[hsw(r, lane*3+1)] = f2bf(n1);
        hb[hsw(r, lane*3+2)] = f2bf(n2);
        hb[hsw(r, 192+lane)] = f2bf(x_skip[(size_t)m*FSKIP + lane]);
    }
    __syncthreads();

    // ---------------- GEMM1: hidden = relu(h @ W1 + b1) ----------------
    // wave wv covers cols [wv*32, wv*32+32)
    f32x4 acc[4][2];
    #pragma unroll
    for (int fi = 0; fi < 4; ++fi)
        #pragma unroll
        for (int ci = 0; ci < 2; ++ci) acc[fi][ci] = (f32x4)0.f;

    for (int ks = 0; ks < 8; ++ks) {
        const int kk = ks*32 + hi*8;
        short8v a[4], bf[2];
        #pragma unroll
        for (int fi = 0; fi < 4; ++fi) {
            const int r = fi*16 + lo;
            a[fi] = *reinterpret_cast<const short8v*>(
                &hb[r*256 + (kk ^ ((lo & 7) << 3))]);
        }
        #pragma unroll
        for (int ci = 0; ci < 2; ++ci) {
            const int cb = wv*32 + ci*16 + lo;
            bf[ci] = *reinterpret_cast<const short8v*>(&wt1[cb*256 + kk]);
        }
        #pragma unroll
        for (int fi = 0; fi < 4; ++fi)
            #pragma unroll
            for (int ci = 0; ci < 2; ++ci)
                acc[fi][ci] = __builtin_amdgcn_mfma_f32_16x16x32_bf16(
                    a[fi], bf[ci], acc[fi][ci], 0, 0, 0);
    }
    __syncthreads();   // all GEMM1 reads of h complete

    {
        float b1v[2];
        #pragma unroll
        for (int ci = 0; ci < 2; ++ci) b1v[ci] = b1[wv*32 + ci*16 + lo];
        #pragma unroll
        for (int fi = 0; fi < 4; ++fi)
            #pragma unroll
            for (int ci = 0; ci < 2; ++ci)
                #pragma unroll
                for (int q = 0; q < 4; ++q) {
                    const int r = fi*16 + hi*4 + q;
                    const int c = wv*32 + ci*16 + lo;
                    hb[hsw(r, c)] = f2bf(fmaxf(acc[fi][ci][q] + b1v[ci], 0.f));
                }
    }
    __syncthreads();

    // ---------------- GEMM2: out = hidden @ W2 + b2 ----------------
    // wave wv covers cols [wv*16, wv*16+16)
    f32x4 acc2[4];
    #pragma unroll
    for (int fi = 0; fi < 4; ++fi) acc2[fi] = (f32x4)0.f;

    for (int ks = 0; ks < 8; ++ks) {
        const int kk = ks*32 + hi*8;
        short8v a[4], bf;
        #pragma unroll
        for (int fi = 0; fi < 4; ++fi) {
            const int r = fi*16 + lo;
            a[fi] = *reinterpret_cast<const short8v*>(
                &hb[r*256 + (kk ^ ((lo & 7) << 3))]);
        }
        {
            const int cb = wv*16 + lo;
            bf = *reinterpret_cast<const short8v*>(&wt2[cb*256 + kk]);
        }
        #pragma unroll
        for (int fi = 0; fi < 4; ++fi)
            acc2[fi] = __builtin_amdgcn_mfma_f32_16x16x32_bf16(
                a[fi], bf, acc2[fi], 0, 0, 0);
    }

    {
        const float b2v = b2[wv*16 + lo];
        #pragma unroll
        for (int fi = 0; fi < 4; ++fi)
            #pragma unroll
            for (int q = 0; q < 4; ++q) {
                const int r = fi*16 + hi*4 + q;
                const int c = wv*16 + lo;
                out[(size_t)(blk*64 + r)*ODIM + c] = acc2[fi][q] + b2v;
            }
    }
}

// ---------------------------------------------------------------------------
// Kernel 2: pass-through tail: pos_skip, batch_skip (int32), lframes_skip
// ---------------------------------------------------------------------------
__global__ __launch_bounds__(256) void tail_kernel(
    const float* __restrict__ pos_skip,
    const int*   __restrict__ batch_skip,
    const float* __restrict__ lframes_skip,
    float* __restrict__ dst)
{
    const int i = blockIdx.x * 256 + threadIdx.x;
    const int P = M_TOT * 3;
    const int Q = P + M_TOT;
    const int R = Q + M_TOT * 9;
    if (i < P)      dst[i] = pos_skip[i];
    else if (i < Q) dst[i] = (float)batch_skip[i - P];
    else if (i < R) dst[i] = lframes_skip[i - Q];
}

extern "C" void kernel_launch(void* const* d_in, const int* in_sizes, int n_in,
                              void* d_out, int out_size, void* d_ws, size_t ws_size,
                              hipStream_t stream) {
    const float* x            = (const float*)d_in[0];
    const float* pos          = (const float*)d_in[1];
    const float* pos_skip     = (const float*)d_in[2];
    const float* x_skip       = (const float*)d_in[3];
    const float* lframes      = (const float*)d_in[4];
    const float* lframes_skip = (const float*)d_in[5];
    const float* W1           = (const float*)d_in[6];
    const float* b1           = (const float*)d_in[7];
    const float* W2           = (const float*)d_in[8];
    const float* b2           = (const float*)d_in[9];
    const int*   batch_skip   = (const int*)d_in[11];

    char* ws = (char*)d_ws;
    unsigned short* wt1 = (unsigned short*)ws;                 // 131072 B
    unsigned short* wt2 = (unsigned short*)(ws + 131072);      // 65536 B
    float* out = (float*)d_out;

    wprep_kernel<<<(256*256 + 256*128) / 256, 256, 0, stream>>>(W1, W2, wt1, wt2);

    fused_kernel<<<M_TOT/64, 512, 0, stream>>>(x, pos, pos_skip, x_skip,
                                               lframes, lframes_skip,
                                               wt1, b1, wt2, b2, out);

    float* tail = out + (size_t)M_TOT * ODIM;
    const int tail_elems = M_TOT * (3 + 1 + 9);
    tail_kernel<<<(tail_elems + 255)/256, 256, 0, stream>>>(
        pos_skip, batch_skip, lframes_skip, tail);
}